// Round 1
// baseline (935.104 us; speedup 1.0000x reference)
//
#include <hip/hip_runtime.h>
#include <math.h>

// ---------------- constants ----------------
#define D_MODEL   1024
#define MEM_SIZE  131072
#define TOP_K     64
#define D_STATE   16
#define D_CONV    4
#define D_INNER   2048
#define DT_RANK   64

// workspace byte offsets (all 256-aligned)
#define WS_CAND1   0u          // u64[16384]  (256 blocks x 64)
#define WS_CAND2   131072u     // u64[1024]
#define WS_IDXF    139264u     // int[64]
#define WS_U       139520u     // f32[64*2048]
#define WS_US      663808u     // f32[64*2048]
#define WS_XDBL    1188096u    // f32[64*96]
#define WS_DELTA   1212672u    // f32[64*2048]
#define WS_Z63     1736960u    // f32[2048]
#define WS_YFIN    1745152u    // f32[2048]
#define WS_CTX     1753344u    // f32[1024]

__device__ __forceinline__ float wave_reduce_add(float v) {
#pragma unroll
  for (int off = 32; off > 0; off >>= 1) v += __shfl_xor(v, off, 64);
  return v;
}

__device__ __forceinline__ unsigned long long pack_key(float sim, int idx) {
  unsigned int fb = __float_as_uint(sim);
  fb = (fb & 0x80000000u) ? ~fb : (fb | 0x80000000u);  // order-preserving map
  return ((unsigned long long)fb << 32) | (unsigned int)(~(unsigned int)idx);
}

// descending bitonic sort of N (pow2) u64 keys in LDS, 256 threads
template <int N>
__device__ __forceinline__ void bitonic_sort_desc(unsigned long long* keys, int tid) {
  for (int k = 2; k <= N; k <<= 1) {
    for (int j = k >> 1; j > 0; j >>= 1) {
      for (int i = tid; i < N; i += 256) {
        int ixj = i ^ j;
        if (ixj > i) {
          unsigned long long a = keys[i], b = keys[ixj];
          bool desc = ((i & k) == 0);
          if (desc ? (a < b) : (a > b)) { keys[i] = b; keys[ixj] = a; }
        }
      }
      __syncthreads();
    }
  }
}

// ---------------- K1: sims + per-block top-64 ----------------
__global__ __launch_bounds__(256) void k_sims(const float* __restrict__ mem,
                                              const float* __restrict__ query,
                                              unsigned long long* __restrict__ cand1) {
  __shared__ float red[4];
  __shared__ unsigned long long keys[512];
  const int tid = threadIdx.x, lane = tid & 63, wave = tid >> 6;

  const float4* q4 = (const float4*)query;
  float4 qf[4];
  float qs = 0.f;
#pragma unroll
  for (int c = 0; c < 4; ++c) {
    qf[c] = q4[c * 64 + lane];
    qs += qf[c].x * qf[c].x + qf[c].y * qf[c].y + qf[c].z * qf[c].z + qf[c].w * qf[c].w;
  }
  qs = wave_reduce_add(qs);
  if (lane == 0) red[wave] = qs;
  __syncthreads();
  const float qn = sqrtf(red[0] + red[1] + red[2] + red[3]);

  const float4* m4 = (const float4*)mem;
  const int base = blockIdx.x * 512 + wave * 128;
  for (int it = 0; it < 64; ++it) {
    const int r0 = base + it * 2, r1 = r0 + 1;
    float d0 = 0.f, s0 = 0.f, d1 = 0.f, s1 = 0.f;
#pragma unroll
    for (int c = 0; c < 4; ++c) {
      float4 a = m4[r0 * 256 + c * 64 + lane];
      float4 b = m4[r1 * 256 + c * 64 + lane];
      d0 += a.x * qf[c].x + a.y * qf[c].y + a.z * qf[c].z + a.w * qf[c].w;
      s0 += a.x * a.x + a.y * a.y + a.z * a.z + a.w * a.w;
      d1 += b.x * qf[c].x + b.y * qf[c].y + b.z * qf[c].z + b.w * qf[c].w;
      s1 += b.x * b.x + b.y * b.y + b.z * b.z + b.w * b.w;
    }
    d0 = wave_reduce_add(d0); s0 = wave_reduce_add(s0);
    d1 = wave_reduce_add(d1); s1 = wave_reduce_add(s1);
    if (lane == 0) {
      float sim0 = d0 / fmaxf(sqrtf(s0) * qn, 1e-8f);
      float sim1 = d1 / fmaxf(sqrtf(s1) * qn, 1e-8f);
      keys[wave * 128 + it * 2]     = pack_key(sim0, r0);
      keys[wave * 128 + it * 2 + 1] = pack_key(sim1, r1);
    }
  }
  __syncthreads();
  bitonic_sort_desc<512>(keys, tid);
  if (tid < 64) cand1[blockIdx.x * 64 + tid] = keys[tid];
}

// ---------------- K2: 16-way merge (1024 -> 64 each) ----------------
__global__ __launch_bounds__(256) void k_merge16(const unsigned long long* __restrict__ in,
                                                 unsigned long long* __restrict__ outk) {
  __shared__ unsigned long long keys[1024];
  const int tid = threadIdx.x;
  for (int i = tid; i < 1024; i += 256) keys[i] = in[blockIdx.x * 1024 + i];
  __syncthreads();
  bitonic_sort_desc<1024>(keys, tid);
  if (tid < 64) outk[blockIdx.x * 64 + tid] = keys[tid];
}

// ---------------- K_usage: copy usage (as float) ----------------
__global__ __launch_bounds__(256) void k_usage(const int* __restrict__ usage_in,
                                               float* __restrict__ usage_out) {
  const int i = blockIdx.x * 256 + threadIdx.x;
  usage_out[i] = (float)usage_in[i];
}

// ---------------- K3: final top-64 + usage bump ----------------
__global__ __launch_bounds__(256) void k_final(const unsigned long long* __restrict__ in,
                                               int* __restrict__ idxf,
                                               float* __restrict__ usage_out) {
  __shared__ unsigned long long keys[1024];
  const int tid = threadIdx.x;
  for (int i = tid; i < 1024; i += 256) keys[i] = in[i];
  __syncthreads();
  bitonic_sort_desc<1024>(keys, tid);
  if (tid < 64) {
    unsigned int low = (unsigned int)(keys[tid] & 0xFFFFFFFFull);
    int idx = (int)(~low);
    idxf[tid] = idx;
    usage_out[idx] += 1.0f;
  }
}

// ---------------- K4: in_proj (u for all l; z only at l=63) ----------------
__global__ __launch_bounds__(256) void k_inproj(const float* __restrict__ mem,
                                                const float* __restrict__ inw,
                                                const int* __restrict__ idxf,
                                                float* __restrict__ u,
                                                float* __restrict__ z63) {
  const int tid = threadIdx.x, lane = tid & 63, wave = tid >> 6;
  const int bid = blockIdx.x;
  const float4* m4 = (const float4*)mem;
  const float4* w4 = (const float4*)inw;
  if (bid < 256) {
    const int e0 = bid * 8 + wave * 2;
    float4 wa[4], wb[4];
#pragma unroll
    for (int c = 0; c < 4; ++c) {
      wa[c] = w4[e0 * 256 + c * 64 + lane];
      wb[c] = w4[(e0 + 1) * 256 + c * 64 + lane];
    }
    for (int l = 0; l < 64; ++l) {
      const int r = idxf[l];
      float da = 0.f, db = 0.f;
#pragma unroll
      for (int c = 0; c < 4; ++c) {
        float4 x = m4[r * 256 + c * 64 + lane];
        da += x.x * wa[c].x + x.y * wa[c].y + x.z * wa[c].z + x.w * wa[c].w;
        db += x.x * wb[c].x + x.y * wb[c].y + x.z * wb[c].z + x.w * wb[c].w;
      }
      da = wave_reduce_add(da);
      db = wave_reduce_add(db);
      if (lane == 0) {
        u[l * 2048 + e0]     = da;
        u[l * 2048 + e0 + 1] = db;
      }
    }
  } else {
    const int wid = (bid - 256) * 4 + wave;  // 0..127
    const int r63 = idxf[63];
    float4 xf[4];
#pragma unroll
    for (int c = 0; c < 4; ++c) xf[c] = m4[r63 * 256 + c * 64 + lane];
    for (int j = 0; j < 16; ++j) {
      const int e = 2048 + wid * 16 + j;
      float dsum = 0.f;
#pragma unroll
      for (int c = 0; c < 4; ++c) {
        float4 w = w4[e * 256 + c * 64 + lane];
        dsum += w.x * xf[c].x + w.y * xf[c].y + w.z * xf[c].z + w.w * xf[c].w;
      }
      dsum = wave_reduce_add(dsum);
      if (lane == 0) z63[e - 2048] = dsum;
    }
  }
}

// ---------------- K6: causal conv (width 4) + SiLU ----------------
__global__ __launch_bounds__(256) void k_conv(const float* __restrict__ u,
                                              const float* __restrict__ cw,
                                              const float* __restrict__ cb,
                                              float* __restrict__ us) {
  const int e = blockIdx.x * 256 + threadIdx.x;  // grid.x = 8
  const int l = blockIdx.y;                      // grid.y = 64
  float acc = cb[e];
#pragma unroll
  for (int j = 0; j < 4; ++j) {
    const int li = l - 3 + j;
    if (li >= 0) acc += u[li * 2048 + e] * cw[e * 4 + j];
  }
  us[l * 2048 + e] = acc / (1.f + __expf(-acc));
}

// ---------------- K7: x_proj (96 outputs per l) ----------------
__global__ __launch_bounds__(256) void k_xproj(const float* __restrict__ us,
                                               const float* __restrict__ xw,
                                               float* __restrict__ xdbl) {
  __shared__ __align__(16) float su[2048];
  const int tid = threadIdx.x, lane = tid & 63, wave = tid >> 6;
  const int l = blockIdx.x;  // grid = 64
  for (int i = tid; i < 2048; i += 256) su[i] = us[l * 2048 + i];
  __syncthreads();
  const float4* su4 = (const float4*)su;
  const float4* xw4 = (const float4*)xw;
  for (int j = wave; j < 96; j += 4) {
    float dsum = 0.f;
#pragma unroll
    for (int c = 0; c < 8; ++c) {
      float4 a = su4[c * 64 + lane];
      float4 w = xw4[j * 512 + c * 64 + lane];
      dsum += a.x * w.x + a.y * w.y + a.z * w.z + a.w * w.w;
    }
    dsum = wave_reduce_add(dsum);
    if (lane == 0) xdbl[l * 96 + j] = dsum;
  }
}

// ---------------- K8: dt_proj + softplus -> delta ----------------
__global__ __launch_bounds__(256) void k_dtproj(const float* __restrict__ xdbl,
                                                const float* __restrict__ dtw,
                                                const float* __restrict__ dtb,
                                                float* __restrict__ delta) {
  const int d = blockIdx.x * 256 + threadIdx.x;  // grid.x = 8
  const int l0 = blockIdx.y * 8;                 // grid.y = 8
  float w[64];
  const float4* dtw4 = (const float4*)dtw;
#pragma unroll
  for (int c = 0; c < 16; ++c) {
    float4 t = dtw4[d * 16 + c];
    w[c * 4] = t.x; w[c * 4 + 1] = t.y; w[c * 4 + 2] = t.z; w[c * 4 + 3] = t.w;
  }
  const float b = dtb[d];
  for (int l = 0; l < 8; ++l) {
    float acc = b;
    const float* arow = xdbl + (l0 + l) * 96;
#pragma unroll
    for (int r = 0; r < 64; ++r) acc += w[r] * arow[r];
    float sp = fmaxf(acc, 0.f) + log1pf(__expf(-fabsf(acc)));
    delta[(l0 + l) * 2048 + d] = sp;
  }
}

// ---------------- K9: selective scan (only y[63] needed) ----------------
__global__ __launch_bounds__(256) void k_scan(const float* __restrict__ delta,
                                              const float* __restrict__ us,
                                              const float* __restrict__ xdbl,
                                              const float* __restrict__ A_log,
                                              const float* __restrict__ Dp,
                                              const float* __restrict__ z63,
                                              float* __restrict__ yfin) {
  const int t = blockIdx.x * 256 + threadIdx.x;  // grid = 128 -> 32768
  const int d = t >> 4, s = t & 15;
  const float A = -__expf(A_log[t]);  // A_log is [d][s] contiguous == [t]
  float h = 0.f;
#pragma unroll 8
  for (int l = 0; l < 64; ++l) {
    float dl = delta[l * 2048 + d];
    float ul = us[l * 2048 + d];
    float bl = xdbl[l * 96 + 64 + s];
    h = __expf(dl * A) * h + dl * bl * ul;
  }
  float v = h * xdbl[63 * 96 + 80 + s];
#pragma unroll
  for (int off = 8; off >= 1; off >>= 1) v += __shfl_xor(v, off, 64);
  if (s == 0) {
    float y = v + us[63 * 2048 + d] * Dp[d];
    float z = z63[d];
    yfin[d] = y * (z / (1.f + __expf(-z)));
  }
}

// ---------------- K10: out_proj (only token 63) ----------------
__global__ __launch_bounds__(256) void k_outproj(const float* __restrict__ yfin,
                                                 const float* __restrict__ ow,
                                                 float* __restrict__ ctx) {
  const int tid = threadIdx.x, lane = tid & 63, wave = tid >> 6;
  const int m = blockIdx.x * 4 + wave;  // grid = 256
  const float4* y4 = (const float4*)yfin;
  const float4* ow4 = (const float4*)ow;
  float dsum = 0.f;
#pragma unroll
  for (int c = 0; c < 8; ++c) {
    float4 w = ow4[m * 512 + c * 64 + lane];
    float4 y = y4[c * 64 + lane];
    dsum += w.x * y.x + w.y * y.y + w.z * y.z + w.w * y.w;
  }
  dsum = wave_reduce_add(dsum);
  if (lane == 0) ctx[m] = dsum;
}

// ---------------- K11: LayerNorm ----------------
__global__ __launch_bounds__(256) void k_ln(const float* __restrict__ ctx,
                                            const float* __restrict__ g,
                                            const float* __restrict__ b,
                                            float* __restrict__ out) {
  __shared__ float red[8];
  const int tid = threadIdx.x, lane = tid & 63, wave = tid >> 6;
  float4 v = ((const float4*)ctx)[tid];
  float s1 = v.x + v.y + v.z + v.w;
  float s2 = v.x * v.x + v.y * v.y + v.z * v.z + v.w * v.w;
  s1 = wave_reduce_add(s1);
  s2 = wave_reduce_add(s2);
  if (lane == 0) { red[wave] = s1; red[4 + wave] = s2; }
  __syncthreads();
  const float mu = (red[0] + red[1] + red[2] + red[3]) * (1.f / 1024.f);
  const float var = (red[4] + red[5] + red[6] + red[7]) * (1.f / 1024.f) - mu * mu;
  const float rs = rsqrtf(var + 1e-5f);
  const int i0 = tid * 4;
  out[i0 + 0] = (v.x - mu) * rs * g[i0 + 0] + b[i0 + 0];
  out[i0 + 1] = (v.y - mu) * rs * g[i0 + 1] + b[i0 + 1];
  out[i0 + 2] = (v.z - mu) * rs * g[i0 + 2] + b[i0 + 2];
  out[i0 + 3] = (v.w - mu) * rs * g[i0 + 3] + b[i0 + 3];
}

extern "C" void kernel_launch(void* const* d_in, const int* in_sizes, int n_in,
                              void* d_out, int out_size, void* d_ws, size_t ws_size,
                              hipStream_t stream) {
  const float* query    = (const float*)d_in[0];
  const float* memory   = (const float*)d_in[1];
  const int*   usage_in = (const int*)d_in[2];
  const float* in_proj  = (const float*)d_in[3];
  const float* conv_w   = (const float*)d_in[4];
  const float* conv_b   = (const float*)d_in[5];
  const float* x_proj   = (const float*)d_in[6];
  const float* dt_proj  = (const float*)d_in[7];
  const float* dt_bias  = (const float*)d_in[8];
  const float* A_log    = (const float*)d_in[9];
  const float* Dp       = (const float*)d_in[10];
  const float* out_proj = (const float*)d_in[11];
  const float* ln_g     = (const float*)d_in[12];
  const float* ln_b     = (const float*)d_in[13];

  char* ws = (char*)d_ws;
  unsigned long long* cand1 = (unsigned long long*)(ws + WS_CAND1);
  unsigned long long* cand2 = (unsigned long long*)(ws + WS_CAND2);
  int*   idxf  = (int*)(ws + WS_IDXF);
  float* u     = (float*)(ws + WS_U);
  float* us_   = (float*)(ws + WS_US);
  float* xdbl  = (float*)(ws + WS_XDBL);
  float* delta = (float*)(ws + WS_DELTA);
  float* z63   = (float*)(ws + WS_Z63);
  float* yfin  = (float*)(ws + WS_YFIN);
  float* ctx   = (float*)(ws + WS_CTX);

  float* out_ln    = (float*)d_out;         // 1024 floats
  float* usage_out = (float*)d_out + 1024;  // 131072 floats

  hipLaunchKernelGGL(k_sims,    dim3(256), dim3(256), 0, stream, memory, query, cand1);
  hipLaunchKernelGGL(k_merge16, dim3(16),  dim3(256), 0, stream, cand1, cand2);
  hipLaunchKernelGGL(k_usage,   dim3(512), dim3(256), 0, stream, usage_in, usage_out);
  hipLaunchKernelGGL(k_final,   dim3(1),   dim3(256), 0, stream, cand2, idxf, usage_out);
  hipLaunchKernelGGL(k_inproj,  dim3(288), dim3(256), 0, stream, memory, in_proj, idxf, u, z63);
  hipLaunchKernelGGL(k_conv,    dim3(8, 64), dim3(256), 0, stream, u, conv_w, conv_b, us_);
  hipLaunchKernelGGL(k_xproj,   dim3(64),  dim3(256), 0, stream, us_, x_proj, xdbl);
  hipLaunchKernelGGL(k_dtproj,  dim3(8, 8), dim3(256), 0, stream, xdbl, dt_proj, dt_bias, delta);
  hipLaunchKernelGGL(k_scan,    dim3(128), dim3(256), 0, stream, delta, us_, xdbl, A_log, Dp, z63, yfin);
  hipLaunchKernelGGL(k_outproj, dim3(256), dim3(256), 0, stream, yfin, out_proj, ctx);
  hipLaunchKernelGGL(k_ln,      dim3(1),   dim3(256), 0, stream, ctx, ln_g, ln_b, out_ln);
}

// Round 3
// 900.196 us; speedup vs baseline: 1.0388x; 1.0388x over previous
//
#include <hip/hip_runtime.h>
#include <math.h>

// ---------------- constants ----------------
#define D_MODEL   1024
#define MEM_SIZE  131072
#define TOP_K     64
#define D_STATE   16
#define D_CONV    4
#define D_INNER   2048
#define DT_RANK   64

// workspace byte offsets
#define WS_CAND1   0u          // u64[32768]  (512 blocks x 64)
#define WS_CAND2   262144u     // u64[2048]
#define WS_CAND3   278528u     // u64[128]
#define WS_IDXF    279552u     // int[64]
#define WS_U       294912u     // f32[64*2048]
#define WS_US      819200u     // f32[64*2048]
#define WS_XDBL    1343488u    // f32[64*96]
#define WS_DELTA   1368064u    // f32[64*2048]
#define WS_Z63     1892352u    // f32[2048]
#define WS_YFIN    1900544u    // f32[2048]
#define WS_CTX     1908736u    // f32[1024]

typedef float vfloat4 __attribute__((ext_vector_type(4)));

__device__ __forceinline__ float wave_reduce_add(float v) {
#pragma unroll
  for (int off = 32; off > 0; off >>= 1) v += __shfl_xor(v, off, 64);
  return v;
}

__device__ __forceinline__ vfloat4 ld_nt(const float* p) {
  return __builtin_nontemporal_load((const vfloat4*)p);
}

__device__ __forceinline__ unsigned long long pack_key(float sim, int idx) {
  unsigned int fb = __float_as_uint(sim);
  fb = (fb & 0x80000000u) ? ~fb : (fb | 0x80000000u);  // order-preserving map
  return ((unsigned long long)fb << 32) | (unsigned int)(~(unsigned int)idx);
}

// descending bitonic sort of N (pow2) u64 keys in LDS, 256 threads
template <int N>
__device__ __forceinline__ void bitonic_sort_desc(unsigned long long* keys, int tid) {
  for (int k = 2; k <= N; k <<= 1) {
    for (int j = k >> 1; j > 0; j >>= 1) {
      for (int i = tid; i < N; i += 256) {
        int ixj = i ^ j;
        if (ixj > i) {
          unsigned long long a = keys[i], b = keys[ixj];
          bool desc = ((i & k) == 0);
          if (desc ? (a < b) : (a > b)) { keys[i] = b; keys[ixj] = a; }
        }
      }
      __syncthreads();
    }
  }
}

// ---------------- K1: sims + per-block top-64 (+ fused usage copy) ----------------
// 512 blocks x 256 thr; 2 blocks/CU -> 8 waves/CU; 4 rows in flight per wave iter.
__global__ __launch_bounds__(256) void k_sims(const float* __restrict__ mem,
                                              const float* __restrict__ query,
                                              const int* __restrict__ usage_in,
                                              float* __restrict__ usage_out,
                                              unsigned long long* __restrict__ cand1) {
  __shared__ float red[4];
  __shared__ unsigned long long keys[256];
  const int tid = threadIdx.x, lane = tid & 63, wave = tid >> 6;

  // fused usage copy (int -> float), one element per thread
  {
    const int gi = blockIdx.x * 256 + tid;
    usage_out[gi] = (float)usage_in[gi];
  }

  const float4* q4 = (const float4*)query;
  float4 qf[4];
  float qs = 0.f;
#pragma unroll
  for (int c = 0; c < 4; ++c) {
    qf[c] = q4[c * 64 + lane];
    qs += qf[c].x * qf[c].x + qf[c].y * qf[c].y + qf[c].z * qf[c].z + qf[c].w * qf[c].w;
  }
  qs = wave_reduce_add(qs);
  if (lane == 0) red[wave] = qs;
  __syncthreads();
  const float qn = sqrtf(red[0] + red[1] + red[2] + red[3]);

  const int base = blockIdx.x * 256 + wave * 64;  // 64 rows per wave
  for (int it = 0; it < 16; ++it) {
    const int r0 = base + it * 4;
    float d[4] = {0.f, 0.f, 0.f, 0.f}, s[4] = {0.f, 0.f, 0.f, 0.f};
#pragma unroll
    for (int c = 0; c < 4; ++c) {
#pragma unroll
      for (int k = 0; k < 4; ++k) {
        vfloat4 a = ld_nt(mem + (size_t)(r0 + k) * 1024 + c * 256 + lane * 4);
        d[k] += a.x * qf[c].x + a.y * qf[c].y + a.z * qf[c].z + a.w * qf[c].w;
        s[k] += a.x * a.x + a.y * a.y + a.z * a.z + a.w * a.w;
      }
    }
#pragma unroll
    for (int k = 0; k < 4; ++k) {
      d[k] = wave_reduce_add(d[k]);
      s[k] = wave_reduce_add(s[k]);
    }
    if (lane == 0) {
#pragma unroll
      for (int k = 0; k < 4; ++k) {
        float sim = d[k] / fmaxf(sqrtf(s[k]) * qn, 1e-8f);
        keys[wave * 64 + it * 4 + k] = pack_key(sim, r0 + k);
      }
    }
  }
  __syncthreads();
  bitonic_sort_desc<256>(keys, tid);
  if (tid < 64) cand1[blockIdx.x * 64 + tid] = keys[tid];
}

// ---------------- K2: merge (1024 -> 64 per block); used twice ----------------
__global__ __launch_bounds__(256) void k_merge16(const unsigned long long* __restrict__ in,
                                                 unsigned long long* __restrict__ outk) {
  __shared__ unsigned long long keys[1024];
  const int tid = threadIdx.x;
  for (int i = tid; i < 1024; i += 256) keys[i] = in[blockIdx.x * 1024 + i];
  __syncthreads();
  bitonic_sort_desc<1024>(keys, tid);
  if (tid < 64) outk[blockIdx.x * 64 + tid] = keys[tid];
}

// ---------------- K3: final top-64 (of 128) + usage bump ----------------
__global__ __launch_bounds__(256) void k_final(const unsigned long long* __restrict__ in,
                                               int* __restrict__ idxf,
                                               float* __restrict__ usage_out) {
  __shared__ unsigned long long keys[128];
  const int tid = threadIdx.x;
  if (tid < 128) keys[tid] = in[tid];
  __syncthreads();
  bitonic_sort_desc<128>(keys, tid);
  if (tid < 64) {
    unsigned int low = (unsigned int)(keys[tid] & 0xFFFFFFFFull);
    int idx = (int)(~low);
    idxf[tid] = idx;
    usage_out[idx] += 1.0f;
  }
}

// ---------------- K4: in_proj (u for all l; z only at l=63) ----------------
__global__ __launch_bounds__(256) void k_inproj(const float* __restrict__ mem,
                                                const float* __restrict__ inw,
                                                const int* __restrict__ idxf,
                                                float* __restrict__ u,
                                                float* __restrict__ z63) {
  const int tid = threadIdx.x, lane = tid & 63, wave = tid >> 6;
  const int bid = blockIdx.x;
  const float4* m4 = (const float4*)mem;
  const float4* w4 = (const float4*)inw;
  if (bid < 256) {
    const int e0 = bid * 8 + wave * 2;
    float4 wa[4], wb[4];
#pragma unroll
    for (int c = 0; c < 4; ++c) {
      wa[c] = w4[e0 * 256 + c * 64 + lane];
      wb[c] = w4[(e0 + 1) * 256 + c * 64 + lane];
    }
    for (int l = 0; l < 64; ++l) {
      const int r = idxf[l];
      float da = 0.f, db = 0.f;
#pragma unroll
      for (int c = 0; c < 4; ++c) {
        float4 x = m4[r * 256 + c * 64 + lane];
        da += x.x * wa[c].x + x.y * wa[c].y + x.z * wa[c].z + x.w * wa[c].w;
        db += x.x * wb[c].x + x.y * wb[c].y + x.z * wb[c].z + x.w * wb[c].w;
      }
      da = wave_reduce_add(da);
      db = wave_reduce_add(db);
      if (lane == 0) {
        u[l * 2048 + e0]     = da;
        u[l * 2048 + e0 + 1] = db;
      }
    }
  } else {
    const int wid = (bid - 256) * 4 + wave;  // 0..127
    const int r63 = idxf[63];
    float4 xf[4];
#pragma unroll
    for (int c = 0; c < 4; ++c) xf[c] = m4[r63 * 256 + c * 64 + lane];
    for (int j = 0; j < 16; ++j) {
      const int e = 2048 + wid * 16 + j;
      float dsum = 0.f;
#pragma unroll
      for (int c = 0; c < 4; ++c) {
        float4 w = w4[e * 256 + c * 64 + lane];
        dsum += w.x * xf[c].x + w.y * xf[c].y + w.z * xf[c].z + w.w * xf[c].w;
      }
      dsum = wave_reduce_add(dsum);
      if (lane == 0) z63[e - 2048] = dsum;
    }
  }
}

// ---------------- K6: causal conv (width 4) + SiLU ----------------
__global__ __launch_bounds__(256) void k_conv(const float* __restrict__ u,
                                              const float* __restrict__ cw,
                                              const float* __restrict__ cb,
                                              float* __restrict__ us) {
  const int e = blockIdx.x * 256 + threadIdx.x;  // grid.x = 8
  const int l = blockIdx.y;                      // grid.y = 64
  float acc = cb[e];
#pragma unroll
  for (int j = 0; j < 4; ++j) {
    const int li = l - 3 + j;
    if (li >= 0) acc += u[li * 2048 + e] * cw[e * 4 + j];
  }
  us[l * 2048 + e] = acc / (1.f + __expf(-acc));
}

// ---------------- K7: x_proj (96 outputs per l) ----------------
__global__ __launch_bounds__(256) void k_xproj(const float* __restrict__ us,
                                               const float* __restrict__ xw,
                                               float* __restrict__ xdbl) {
  __shared__ __align__(16) float su[2048];
  const int tid = threadIdx.x, lane = tid & 63, wave = tid >> 6;
  const int l = blockIdx.x;  // grid = 64
  for (int i = tid; i < 2048; i += 256) su[i] = us[l * 2048 + i];
  __syncthreads();
  const float4* su4 = (const float4*)su;
  const float4* xw4 = (const float4*)xw;
  for (int j = wave; j < 96; j += 4) {
    float dsum = 0.f;
#pragma unroll
    for (int c = 0; c < 8; ++c) {
      float4 a = su4[c * 64 + lane];
      float4 w = xw4[j * 512 + c * 64 + lane];
      dsum += a.x * w.x + a.y * w.y + a.z * w.z + a.w * w.w;
    }
    dsum = wave_reduce_add(dsum);
    if (lane == 0) xdbl[l * 96 + j] = dsum;
  }
}

// ---------------- K8: dt_proj + softplus -> delta ----------------
__global__ __launch_bounds__(256) void k_dtproj(const float* __restrict__ xdbl,
                                                const float* __restrict__ dtw,
                                                const float* __restrict__ dtb,
                                                float* __restrict__ delta) {
  const int d = blockIdx.x * 256 + threadIdx.x;  // grid.x = 8
  const int l0 = blockIdx.y * 8;                 // grid.y = 8
  float w[64];
  const float4* dtw4 = (const float4*)dtw;
#pragma unroll
  for (int c = 0; c < 16; ++c) {
    float4 t = dtw4[d * 16 + c];
    w[c * 4] = t.x; w[c * 4 + 1] = t.y; w[c * 4 + 2] = t.z; w[c * 4 + 3] = t.w;
  }
  const float b = dtb[d];
  for (int l = 0; l < 8; ++l) {
    float acc = b;
    const float* arow = xdbl + (l0 + l) * 96;
#pragma unroll
    for (int r = 0; r < 64; ++r) acc += w[r] * arow[r];
    float sp = fmaxf(acc, 0.f) + log1pf(__expf(-fabsf(acc)));
    delta[(l0 + l) * 2048 + d] = sp;
  }
}

// ---------------- K9: selective scan (only y[63] needed) ----------------
__global__ __launch_bounds__(256) void k_scan(const float* __restrict__ delta,
                                              const float* __restrict__ us,
                                              const float* __restrict__ xdbl,
                                              const float* __restrict__ A_log,
                                              const float* __restrict__ Dp,
                                              const float* __restrict__ z63,
                                              float* __restrict__ yfin) {
  const int t = blockIdx.x * 256 + threadIdx.x;  // grid = 128 -> 32768
  const int d = t >> 4, s = t & 15;
  const float A = -__expf(A_log[t]);  // A_log is [d][s] contiguous == [t]
  float h = 0.f;
#pragma unroll 8
  for (int l = 0; l < 64; ++l) {
    float dl = delta[l * 2048 + d];
    float ul = us[l * 2048 + d];
    float bl = xdbl[l * 96 + 64 + s];
    h = __expf(dl * A) * h + dl * bl * ul;
  }
  float v = h * xdbl[63 * 96 + 80 + s];
#pragma unroll
  for (int off = 8; off >= 1; off >>= 1) v += __shfl_xor(v, off, 64);
  if (s == 0) {
    float y = v + us[63 * 2048 + d] * Dp[d];
    float z = z63[d];
    yfin[d] = y * (z / (1.f + __expf(-z)));
  }
}

// ---------------- K10: out_proj (only token 63) ----------------
__global__ __launch_bounds__(256) void k_outproj(const float* __restrict__ yfin,
                                                 const float* __restrict__ ow,
                                                 float* __restrict__ ctx) {
  const int tid = threadIdx.x, lane = tid & 63, wave = tid >> 6;
  const int m = blockIdx.x * 4 + wave;  // grid = 256
  const float4* y4 = (const float4*)yfin;
  const float4* ow4 = (const float4*)ow;
  float dsum = 0.f;
#pragma unroll
  for (int c = 0; c < 8; ++c) {
    float4 w = ow4[m * 512 + c * 64 + lane];
    float4 y = y4[c * 64 + lane];
    dsum += w.x * y.x + w.y * y.y + w.z * y.z + w.w * y.w;
  }
  dsum = wave_reduce_add(dsum);
  if (lane == 0) ctx[m] = dsum;
}

// ---------------- K11: LayerNorm ----------------
__global__ __launch_bounds__(256) void k_ln(const float* __restrict__ ctx,
                                            const float* __restrict__ g,
                                            const float* __restrict__ b,
                                            float* __restrict__ out) {
  __shared__ float red[8];
  const int tid = threadIdx.x, lane = tid & 63, wave = tid >> 6;
  float4 v = ((const float4*)ctx)[tid];
  float s1 = v.x + v.y + v.z + v.w;
  float s2 = v.x * v.x + v.y * v.y + v.z * v.z + v.w * v.w;
  s1 = wave_reduce_add(s1);
  s2 = wave_reduce_add(s2);
  if (lane == 0) { red[wave] = s1; red[4 + wave] = s2; }
  __syncthreads();
  const float mu = (red[0] + red[1] + red[2] + red[3]) * (1.f / 1024.f);
  const float var = (red[4] + red[5] + red[6] + red[7]) * (1.f / 1024.f) - mu * mu;
  const float rs = rsqrtf(var + 1e-5f);
  const int i0 = tid * 4;
  out[i0 + 0] = (v.x - mu) * rs * g[i0 + 0] + b[i0 + 0];
  out[i0 + 1] = (v.y - mu) * rs * g[i0 + 1] + b[i0 + 1];
  out[i0 + 2] = (v.z - mu) * rs * g[i0 + 2] + b[i0 + 2];
  out[i0 + 3] = (v.w - mu) * rs * g[i0 + 3] + b[i0 + 3];
}

extern "C" void kernel_launch(void* const* d_in, const int* in_sizes, int n_in,
                              void* d_out, int out_size, void* d_ws, size_t ws_size,
                              hipStream_t stream) {
  const float* query    = (const float*)d_in[0];
  const float* memory   = (const float*)d_in[1];
  const int*   usage_in = (const int*)d_in[2];
  const float* in_proj  = (const float*)d_in[3];
  const float* conv_w   = (const float*)d_in[4];
  const float* conv_b   = (const float*)d_in[5];
  const float* x_proj   = (const float*)d_in[6];
  const float* dt_proj  = (const float*)d_in[7];
  const float* dt_bias  = (const float*)d_in[8];
  const float* A_log    = (const float*)d_in[9];
  const float* Dp       = (const float*)d_in[10];
  const float* out_proj = (const float*)d_in[11];
  const float* ln_g     = (const float*)d_in[12];
  const float* ln_b     = (const float*)d_in[13];

  char* ws = (char*)d_ws;
  unsigned long long* cand1 = (unsigned long long*)(ws + WS_CAND1);
  unsigned long long* cand2 = (unsigned long long*)(ws + WS_CAND2);
  unsigned long long* cand3 = (unsigned long long*)(ws + WS_CAND3);
  int*   idxf  = (int*)(ws + WS_IDXF);
  float* u     = (float*)(ws + WS_U);
  float* us_   = (float*)(ws + WS_US);
  float* xdbl  = (float*)(ws + WS_XDBL);
  float* delta = (float*)(ws + WS_DELTA);
  float* z63   = (float*)(ws + WS_Z63);
  float* yfin  = (float*)(ws + WS_YFIN);
  float* ctx   = (float*)(ws + WS_CTX);

  float* out_ln    = (float*)d_out;         // 1024 floats
  float* usage_out = (float*)d_out + 1024;  // 131072 floats

  hipLaunchKernelGGL(k_sims,    dim3(512), dim3(256), 0, stream, memory, query, usage_in, usage_out, cand1);
  hipLaunchKernelGGL(k_merge16, dim3(32),  dim3(256), 0, stream, cand1, cand2);
  hipLaunchKernelGGL(k_merge16, dim3(2),   dim3(256), 0, stream, cand2, cand3);
  hipLaunchKernelGGL(k_final,   dim3(1),   dim3(256), 0, stream, cand3, idxf, usage_out);
  hipLaunchKernelGGL(k_inproj,  dim3(288), dim3(256), 0, stream, memory, in_proj, idxf, u, z63);
  hipLaunchKernelGGL(k_conv,    dim3(8, 64), dim3(256), 0, stream, u, conv_w, conv_b, us_);
  hipLaunchKernelGGL(k_xproj,   dim3(64),  dim3(256), 0, stream, us_, x_proj, xdbl);
  hipLaunchKernelGGL(k_dtproj,  dim3(8, 8), dim3(256), 0, stream, xdbl, dt_proj, dt_bias, delta);
  hipLaunchKernelGGL(k_scan,    dim3(128), dim3(256), 0, stream, delta, us_, xdbl, A_log, Dp, z63, yfin);
  hipLaunchKernelGGL(k_outproj, dim3(256), dim3(256), 0, stream, yfin, out_proj, ctx);
  hipLaunchKernelGGL(k_ln,      dim3(1),   dim3(256), 0, stream, ctx, ln_g, ln_b, out_ln);
}